// Round 14
// baseline (57.683 us; speedup 1.0000x reference)
//
#include <hip/hip_runtime.h>
#include <hip/hip_fp16.h>

#define B_ 4
#define F_ 2
#define C_ 16
#define H_ 48
#define W_ 160
#define D_ 96
#define HW_ (H_*W_)
#define PIX_ 64            // pixels per block (one wave = 64 px at one depth-group)
#define GRP_ 8             // depth groups per block (PIX_*GRP_ = 512 threads)
#define BINS_ (D_/GRP_)    // 12 bins per group
#define NCHUNK_ (HW_/PIX_) // 120
#define NPAIR_ 24          // row pairs per copy
// pair block: per x, 2 rows x 16ch fp16 = 64B; quad(x..x+1) = 128B contiguous

// Prep: mats (block 0) + cur transpose fp16 + look -> row-pair-interleaved
// fp16 layout [slice][copy][pair][x][2rows][16ch]. Each look value is written
// to copy0 (pair y>>1, slot y&1) and copy1 (pair/slot per parity).
__global__ __launch_bounds__(256) void prep_kernel(
    const float* __restrict__ cur, const float* __restrict__ look,
    const float* __restrict__ poses, const float* __restrict__ Kmat,
    __half* __restrict__ curH, __half* __restrict__ pairH,
    float* __restrict__ mats)
{
  int tid = threadIdx.x;
  int bid = blockIdx.x;
  if (bid == 0 && tid < B_*F_) {
    int t = tid, b = t / F_;
    const float* T  = poses + t*16;
    const float* Kb = Kmat + b*16;
    float sum = 0.f;
    #pragma unroll
    for (int i = 0; i < 16; ++i) sum += T[i];
    #pragma unroll
    for (int i = 0; i < 3; ++i) {
      #pragma unroll
      for (int j = 0; j < 4; ++j) {
        float v = 0.f;
        #pragma unroll
        for (int k = 0; k < 4; ++k) v += Kb[i*4+k] * T[k*4+j];
        mats[t*16 + i*4 + j] = v;
      }
    }
    mats[t*16 + 12] = (sum != 0.f) ? 1.f : 0.f;
  }
  int px_l = tid & 127;
  int h    = tid >> 7;                 // 0 or 1 (channel half)
  int gp   = bid*128 + px_l;           // global pixel id over cur then look
  if (gp < B_*HW_) {
    int hw = gp % HW_, s = gp / HW_;
    const float* src = cur + (size_t)s*C_*HW_ + hw;
    int c0 = h*8;
    __half2 hh[4];
    #pragma unroll
    for (int j = 0; j < 4; ++j)
      hh[j] = __floats2half2_rn(src[(size_t)(c0+2*j)*HW_], src[(size_t)(c0+2*j+1)*HW_]);
    *reinterpret_cast<uint4*>(curH + (size_t)gp*C_ + c0) = *reinterpret_cast<uint4*>(&hh[0]);
  } else {
    int j = gp - B_*HW_;               // look pixel id, s in [0, B*F)
    int hw = j % HW_, s = j / HW_;
    int x = hw % W_, y = hw / W_;
    const float* src = look + (size_t)s*C_*HW_ + hw;
    int c0 = h*8;
    __half2 hh[4];
    #pragma unroll
    for (int jj = 0; jj < 4; ++jj)
      hh[jj] = __floats2half2_rn(src[(size_t)(c0+2*jj)*HW_], src[(size_t)(c0+2*jj+1)*HW_]);
    uint4 val = *reinterpret_cast<uint4*>(&hh[0]);
    // copy 0: pair = y>>1, slot = y&1
    {
      size_t off = ((((size_t)(s*2 + 0)*NPAIR_ + (y>>1))*W_ + x)*32) + (size_t)(y&1)*16 + h*8;
      *reinterpret_cast<uint4*>(pairH + off) = val;
    }
    // copy 1: rows (2p+1, 2p+2). y odd -> p=y>>1 slot0; y even>=2 -> p=y/2-1 slot1
    if (y >= 1) {
      int p1   = (y & 1) ? (y>>1) : ((y>>1) - 1);
      int slot = (y & 1) ? 0 : 1;
      size_t off = ((((size_t)(s*2 + 1)*NPAIR_ + p1)*W_ + x)*32) + (size_t)slot*16 + h*8;
      *reinterpret_cast<uint4*>(pairH + off) = val;
    }
  }
}

// Fused cost + finalize. Block = 64 pixels x 8 depth-groups (12 bins each).
// Taps from the row-pair layout: one 128B contiguous 64B-aligned block per
// quad (copy = yi&1, pair = yi>>1) -> 2 cache lines per lane-quad.
__global__ __launch_bounds__(512, 4) void fused_kernel(
    const __half* __restrict__ curH, const __half* __restrict__ pairH,
    const float* __restrict__ mats, const float* __restrict__ invK,
    const float* __restrict__ dbins,
    float* __restrict__ cost, float* __restrict__ missing)
{
  int tid = threadIdx.x;
  int pix = tid & (PIX_-1);
  int grp = tid >> 6;                 // 0..7 (wave index)
  int bid = blockIdx.x;
  int chunk = bid % NCHUNK_;
  int b = bid / NCHUNK_;
  int hw = chunk*PIX_ + pix;
  int x = hw % W_, y = hw / W_;
  size_t obase = ((size_t)(b*D_ + grp*BINS_))*HW_ + hw;

  float res[BINS_];
  #pragma unroll
  for (int dd = 0; dd < BINS_; ++dd) res[dd] = 0.f;
  float lmax = 0.f;
  bool interior = (x >= 2 && x < W_-2 && y >= 2 && y < H_-2);
  if (interior) {
    const float* iK = invK + b*16;
    float xf = (float)x, yf = (float)y;
    float r0 = iK[0]*xf + iK[1]*yf + iK[2];
    float r1 = iK[4]*xf + iK[5]*yf + iK[6];
    float r2 = iK[8]*xf + iK[9]*yf + iK[10];
    __half2 cc2[8];
    {
      const uint4* cur4 = reinterpret_cast<const uint4*>(curH + (size_t)(b*HW_ + hw)*C_);
      *reinterpret_cast<uint4*>(&cc2[0]) = cur4[0];
      *reinterpret_cast<uint4*>(&cc2[4]) = cur4[1];
    }
    // wave-uniform projection rows (b uniform per block, f static)
    float Mv[2][13];
    #pragma unroll
    for (int f = 0; f < F_; ++f) {
      const float* Mt = mats + (b*F_+f)*16;
      #pragma unroll
      for (int i = 0; i < 13; ++i) Mv[f][i] = Mt[i];
    }
    #pragma unroll
    for (int dd = 0; dd < BINS_; ++dd) {
      float dep = dbins[grp*BINS_ + dd];
      float p0 = dep*r0, p1 = dep*r1, p2 = dep*r2;
      // --- phase 1: addresses + weights for both frames ---
      const uint4* bases[F_];
      float w00f[F_], w10f[F_], w01f[F_], w11f[F_];
      bool okf[F_];
      #pragma unroll
      for (int f = 0; f < F_; ++f) {
        float camx = Mv[f][0]*p0 + Mv[f][1]*p1 + Mv[f][2] *p2 + Mv[f][3];
        float camy = Mv[f][4]*p0 + Mv[f][5]*p1 + Mv[f][6] *p2 + Mv[f][7];
        float camz = Mv[f][8]*p0 + Mv[f][9]*p1 + Mv[f][10]*p2 + Mv[f][11];
        float z  = camz + 1e-7f;
        float px = camx / z;
        float py = camy / z;
        okf[f] = (Mv[f][12] != 0.f) && (px >= 2.f) && (px <= (float)(W_-2))
                                    && (py >= 2.f) && (py <= (float)(H_-2));
        float x0 = floorf(px), y0 = floorf(py);
        float fx = px - x0, fy = py - y0;
        fx = fminf(fmaxf(fx, 0.f), 1.f);
        fy = fminf(fmaxf(fy, 0.f), 1.f);
        int xi = min(max((int)x0, 0), W_-2);
        int yi = min(max((int)y0, 0), H_-2);
        int c  = yi & 1;
        int p  = yi >> 1;
        // uint4 index: 4 per 64B x-block
        bases[f] = reinterpret_cast<const uint4*>(pairH)
                 + (((size_t)((b*F_+f)*2 + c)*NPAIR_ + p)*W_ + xi)*4;
        w00f[f] = (1.f-fx)*(1.f-fy); w10f[f] = fx*(1.f-fy);
        w01f[f] = (1.f-fx)*fy;       w11f[f] = fx*fy;
      }
      // --- phase 2: issue all 16 tap loads (each frame: 128B contiguous) ---
      uint4 t[16];
      #pragma unroll
      for (int f = 0; f < F_; ++f) {
        #pragma unroll
        for (int i = 0; i < 8; ++i) t[f*8+i] = bases[f][i];
      }
      // --- phase 3: fp16 interpolation + L1 diff ---
      // block layout: t[0..1]=x0 row0 (a00), t[2..3]=x0 row1 (a01),
      //               t[4..5]=x1 row0 (a10), t[6..7]=x1 row1 (a11)
      float costsum = 0.f, cnt = 0.f;
      #pragma unroll
      for (int f = 0; f < F_; ++f) {
        __half2 w00h = __float2half2_rn(w00f[f]);
        __half2 w10h = __float2half2_rn(w10f[f]);
        __half2 w01h = __float2half2_rn(w01f[f]);
        __half2 w11h = __float2half2_rn(w11f[f]);
        const __half2* a00 = reinterpret_cast<const __half2*>(&t[f*8+0]);
        const __half2* a01 = reinterpret_cast<const __half2*>(&t[f*8+2]);
        const __half2* a10 = reinterpret_cast<const __half2*>(&t[f*8+4]);
        const __half2* a11 = reinterpret_cast<const __half2*>(&t[f*8+6]);
        __half2 acc0 = __float2half2_rn(0.f);
        __half2 acc1 = __float2half2_rn(0.f);
        #pragma unroll
        for (int i = 0; i < 8; ++i) {
          __half2 v = __hmul2(w00h, a00[i]);
          v = __hfma2(w10h, a10[i], v);
          v = __hfma2(w01h, a01[i], v);
          v = __hfma2(w11h, a11[i], v);
          __half2 dsub = __habs2(__hsub2(v, cc2[i]));
          if (i & 1) acc1 = __hadd2(acc1, dsub);
          else       acc0 = __hadd2(acc0, dsub);
        }
        float2 f0 = __half22float2(acc0);
        float2 f1 = __half22float2(acc1);
        float s = (f0.x + f0.y) + (f1.x + f1.y);
        float diffs = s * (1.f/16.f);
        diffs = okf[f] ? diffs : 0.f;
        costsum += diffs;
        cnt     += (diffs > 0.f) ? 1.f : 0.f;
      }
      float r = costsum / (cnt + 1e-7f);
      res[dd] = r;
      lmax = fmaxf(lmax, r);
    }
  }

  // per-pixel max over the 8 depth-groups
  __shared__ float lmaxs[GRP_][PIX_];
  lmaxs[grp][pix] = lmax;
  __syncthreads();
  float pmax = lmaxs[0][pix];
  #pragma unroll
  for (int g = 1; g < GRP_; ++g) pmax = fmaxf(pmax, lmaxs[g][pix]);

  // write cost (missing-filled) + missing, straight from registers (nt stores)
  #pragma unroll
  for (int dd = 0; dd < BINS_; ++dd) {
    size_t o = obase + (size_t)dd*HW_;
    float v = res[dd];
    float miss = (v == 0.f) ? 1.f : 0.f;
    __builtin_nontemporal_store(miss ? pmax : v, &cost[o]);
    __builtin_nontemporal_store(miss, &missing[o]);
  }
}

extern "C" void kernel_launch(void* const* d_in, const int* in_sizes, int n_in,
                              void* d_out, int out_size, void* d_ws, size_t ws_size,
                              hipStream_t stream) {
  const float* cur   = (const float*)d_in[0];
  const float* look  = (const float*)d_in[1];
  const float* poses = (const float*)d_in[2];
  const float* Km    = (const float*)d_in[3];
  const float* invK  = (const float*)d_in[4];
  const float* dbins = (const float*)d_in[5];

  float* out_cost = (float*)d_out;
  float* out_miss = out_cost + (size_t)B_*D_*HW_;

  char*   ws    = (char*)d_ws;
  float*  mats  = (float*)ws;                                       // 128 floats
  __half* curH  = (__half*)(ws + 1024);                             // B*HW*16 f16
  // pair layout: B*F slices x 2 copies x NPAIR_ x W_ x 64B
  __half* pairH = (__half*)(ws + 1024 + (size_t)B_*HW_*C_*2);

  prep_kernel<<<(B_*HW_ + B_*F_*HW_)/128, 256, 0, stream>>>(
      cur, look, poses, Km, curH, pairH, mats);
  fused_kernel<<<B_*NCHUNK_, 512, 0, stream>>>(
      curH, pairH, mats, invK, dbins, out_cost, out_miss);
}

// Round 15
// 56.412 us; speedup vs baseline: 1.0225x; 1.0225x over previous
//
#include <hip/hip_runtime.h>
#include <hip/hip_fp16.h>

#define B_ 4
#define F_ 2
#define C_ 16
#define H_ 48
#define W_ 160
#define D_ 96
#define HW_ (H_*W_)
#define PIX_ 32            // pixels per wave (x 2 channel-halves = 64 lanes)
#define GRP_ 8             // depth groups per block (8 waves = 512 threads)
#define BINS_ (D_/GRP_)    // 12 bins per group
#define NCHUNK_ (HW_/PIX_) // 240

// Prep: mats (block 0) + transpose/fp16 of cur and look (interleaved [px][16ch]).
__global__ __launch_bounds__(256) void prep_kernel(
    const float* __restrict__ cur, const float* __restrict__ look,
    const float* __restrict__ poses, const float* __restrict__ Kmat,
    __half* __restrict__ curH, __half* __restrict__ lookH,
    float* __restrict__ mats)
{
  int tid = threadIdx.x;
  int bid = blockIdx.x;
  if (bid == 0 && tid < B_*F_) {
    int t = tid, b = t / F_;
    const float* T  = poses + t*16;
    const float* Kb = Kmat + b*16;
    float sum = 0.f;
    #pragma unroll
    for (int i = 0; i < 16; ++i) sum += T[i];
    #pragma unroll
    for (int i = 0; i < 3; ++i) {
      #pragma unroll
      for (int j = 0; j < 4; ++j) {
        float v = 0.f;
        #pragma unroll
        for (int k = 0; k < 4; ++k) v += Kb[i*4+k] * T[k*4+j];
        mats[t*16 + i*4 + j] = v;
      }
    }
    mats[t*16 + 12] = (sum != 0.f) ? 1.f : 0.f;
  }
  int px_l = tid & 127;
  int h    = tid >> 7;                 // 0 or 1 (channel half)
  int gp   = bid*128 + px_l;           // global pixel id over cur then look
  const float* src;
  __half* dst;
  int hw, c0 = h*8;
  if (gp < B_*HW_) {
    hw = gp % HW_;
    int s = gp / HW_;
    src = cur + (size_t)s*C_*HW_ + hw;
    dst = curH + (size_t)gp*C_ + c0;
  } else {
    int j = gp - B_*HW_;
    hw = j % HW_;
    int s = j / HW_;
    src = look + (size_t)s*C_*HW_ + hw;
    dst = lookH + (size_t)j*C_ + c0;
  }
  __half2 hh[4];
  #pragma unroll
  for (int j = 0; j < 4; ++j)
    hh[j] = __floats2half2_rn(src[(size_t)(c0+2*j)*HW_], src[(size_t)(c0+2*j+1)*HW_]);
  *reinterpret_cast<uint4*>(dst) = *reinterpret_cast<uint4*>(&hh[0]);
}

// Fused cost + finalize. Wave = 32 pixels x 2 channel-halves (lane = 2*px+h);
// each lane gathers only its 8 channels (16B) per tap -> dense 16B lane
// stride (~16 lines/instr vs 32). Pair sum completed via shfl_xor(s,1).
// Block = 8 waves = 8 depth-groups of the same 32-pixel chunk.
__global__ __launch_bounds__(512, 4) void fused_kernel(
    const __half* __restrict__ curH, const __half* __restrict__ lookH,
    const float* __restrict__ mats, const float* __restrict__ invK,
    const float* __restrict__ dbins,
    float* __restrict__ cost, float* __restrict__ missing)
{
  int tid  = threadIdx.x;
  int lane = tid & 63;
  int px_l = lane >> 1;               // 0..31
  int h    = lane & 1;                // channel half
  int grp  = tid >> 6;                // 0..7 (wave index)
  int bid  = blockIdx.x;
  int chunk = bid % NCHUNK_;
  int b = bid / NCHUNK_;
  int hw = chunk*PIX_ + px_l;
  int x = hw % W_, y = hw / W_;
  size_t obase = ((size_t)(b*D_ + grp*BINS_))*HW_ + hw;

  float res[BINS_];
  #pragma unroll
  for (int dd = 0; dd < BINS_; ++dd) res[dd] = 0.f;
  float lmax = 0.f;
  bool interior = (x >= 2 && x < W_-2 && y >= 2 && y < H_-2);  // pair-uniform
  if (interior) {
    const float* iK = invK + b*16;
    float xf = (float)x, yf = (float)y;
    float r0 = iK[0]*xf + iK[1]*yf + iK[2];
    float r1 = iK[4]*xf + iK[5]*yf + iK[6];
    float r2 = iK[8]*xf + iK[9]*yf + iK[10];
    // this half's 8 current-feature channels (dense 16B-stride wave load)
    __half2 cc2[4];
    *reinterpret_cast<uint4*>(&cc2[0]) =
        *reinterpret_cast<const uint4*>(curH + (size_t)(b*HW_ + hw)*C_ + h*8);
    // wave-uniform projection rows
    float Mv[2][13];
    #pragma unroll
    for (int f = 0; f < F_; ++f) {
      const float* Mt = mats + (b*F_+f)*16;
      #pragma unroll
      for (int i = 0; i < 13; ++i) Mv[f][i] = Mt[i];
    }
    #pragma unroll
    for (int dd = 0; dd < BINS_; ++dd) {
      float dep = dbins[grp*BINS_ + dd];
      float p0 = dep*r0, p1 = dep*r1, p2 = dep*r2;
      // --- phase 1: addresses + weights for both frames (pair-identical) ---
      const __half* bases[F_];
      float w00f[F_], w10f[F_], w01f[F_], w11f[F_];
      bool okf[F_];
      #pragma unroll
      for (int f = 0; f < F_; ++f) {
        float camx = Mv[f][0]*p0 + Mv[f][1]*p1 + Mv[f][2] *p2 + Mv[f][3];
        float camy = Mv[f][4]*p0 + Mv[f][5]*p1 + Mv[f][6] *p2 + Mv[f][7];
        float camz = Mv[f][8]*p0 + Mv[f][9]*p1 + Mv[f][10]*p2 + Mv[f][11];
        float z  = camz + 1e-7f;
        float px = camx / z;
        float py = camy / z;
        okf[f] = (Mv[f][12] != 0.f) && (px >= 2.f) && (px <= (float)(W_-2))
                                    && (py >= 2.f) && (py <= (float)(H_-2));
        float x0 = floorf(px), y0 = floorf(py);
        float fx = px - x0, fy = py - y0;
        fx = fminf(fmaxf(fx, 0.f), 1.f);
        fy = fminf(fmaxf(fy, 0.f), 1.f);
        int xi = min(max((int)x0, 0), W_-2);
        int yi = min(max((int)y0, 0), H_-2);
        bases[f] = lookH + ((size_t)((b*F_+f)*HW_) + yi*W_ + xi)*C_ + h*8;
        w00f[f] = (1.f-fx)*(1.f-fy); w10f[f] = fx*(1.f-fy);
        w01f[f] = (1.f-fx)*fy;       w11f[f] = fx*fy;
      }
      // --- phase 2: issue all 8 tap loads (16B each, this half only) ---
      uint4 t[8];
      #pragma unroll
      for (int f = 0; f < F_; ++f) {
        const __half* bp = bases[f];
        t[f*4+0] = *reinterpret_cast<const uint4*>(bp);              // tap00
        t[f*4+1] = *reinterpret_cast<const uint4*>(bp + C_);         // tap10
        t[f*4+2] = *reinterpret_cast<const uint4*>(bp + W_*C_);      // tap01
        t[f*4+3] = *reinterpret_cast<const uint4*>(bp + W_*C_ + C_); // tap11
      }
      // --- phase 3: fp16 interpolation + L1 diff, pair-sum via shfl ---
      float costsum = 0.f, cnt = 0.f;
      #pragma unroll
      for (int f = 0; f < F_; ++f) {
        __half2 w00h = __float2half2_rn(w00f[f]);
        __half2 w10h = __float2half2_rn(w10f[f]);
        __half2 w01h = __float2half2_rn(w01f[f]);
        __half2 w11h = __float2half2_rn(w11f[f]);
        const __half2* a00 = reinterpret_cast<const __half2*>(&t[f*4+0]);
        const __half2* a10 = reinterpret_cast<const __half2*>(&t[f*4+1]);
        const __half2* a01 = reinterpret_cast<const __half2*>(&t[f*4+2]);
        const __half2* a11 = reinterpret_cast<const __half2*>(&t[f*4+3]);
        __half2 acc0 = __float2half2_rn(0.f);
        __half2 acc1 = __float2half2_rn(0.f);
        #pragma unroll
        for (int i = 0; i < 4; ++i) {
          __half2 v = __hmul2(w00h, a00[i]);
          v = __hfma2(w10h, a10[i], v);
          v = __hfma2(w01h, a01[i], v);
          v = __hfma2(w11h, a11[i], v);
          __half2 dsub = __habs2(__hsub2(v, cc2[i]));
          if (i & 1) acc1 = __hadd2(acc1, dsub);
          else       acc0 = __hadd2(acc0, dsub);
        }
        float2 f0 = __half22float2(acc0);
        float2 f1 = __half22float2(acc1);
        float s_half = (f0.x + f0.y) + (f1.x + f1.y);
        float s = s_half + __shfl_xor(s_half, 1, 64);   // both halves -> full 16ch
        float diffs = s * (1.f/16.f);
        diffs = okf[f] ? diffs : 0.f;
        costsum += diffs;
        cnt     += (diffs > 0.f) ? 1.f : 0.f;
      }
      float r = costsum / (cnt + 1e-7f);
      res[dd] = r;
      lmax = fmaxf(lmax, r);
    }
  }

  // per-pixel max over the 8 depth-groups (h==0 lanes carry the result)
  __shared__ float lmaxs[GRP_][PIX_];
  if (h == 0) lmaxs[grp][px_l] = lmax;
  __syncthreads();
  float pmax = lmaxs[0][px_l];
  #pragma unroll
  for (int g = 1; g < GRP_; ++g) pmax = fmaxf(pmax, lmaxs[g][px_l]);

  // write cost (missing-filled) + missing from h==0 lanes (nt stores)
  if (h == 0) {
    #pragma unroll
    for (int dd = 0; dd < BINS_; ++dd) {
      size_t o = obase + (size_t)dd*HW_;
      float v = res[dd];
      float miss = (v == 0.f) ? 1.f : 0.f;
      __builtin_nontemporal_store(miss ? pmax : v, &cost[o]);
      __builtin_nontemporal_store(miss, &missing[o]);
    }
  }
}

extern "C" void kernel_launch(void* const* d_in, const int* in_sizes, int n_in,
                              void* d_out, int out_size, void* d_ws, size_t ws_size,
                              hipStream_t stream) {
  const float* cur   = (const float*)d_in[0];
  const float* look  = (const float*)d_in[1];
  const float* poses = (const float*)d_in[2];
  const float* Km    = (const float*)d_in[3];
  const float* invK  = (const float*)d_in[4];
  const float* dbins = (const float*)d_in[5];

  float* out_cost = (float*)d_out;
  float* out_miss = out_cost + (size_t)B_*D_*HW_;

  char*   ws    = (char*)d_ws;
  float*  mats  = (float*)ws;                                       // 128 floats
  __half* curH  = (__half*)(ws + 1024);                             // B*HW*C f16
  __half* lookH = (__half*)(ws + 1024 + (size_t)B_*HW_*C_*2);       // B*F*HW*C f16

  prep_kernel<<<(B_*HW_ + B_*F_*HW_)/128, 256, 0, stream>>>(
      cur, look, poses, Km, curH, lookH, mats);
  fused_kernel<<<B_*NCHUNK_, 512, 0, stream>>>(
      curH, lookH, mats, invK, dbins, out_cost, out_miss);
}

// Round 16
// 52.522 us; speedup vs baseline: 1.0983x; 1.0741x over previous
//
#include <hip/hip_runtime.h>
#include <hip/hip_fp16.h>

#define B_ 4
#define F_ 2
#define C_ 16
#define H_ 48
#define W_ 160
#define D_ 96
#define HW_ (H_*W_)
#define PIX_ 32            // pixels per wave (x 2 lanes/pixel = 64 lanes)
#define GRP_ 8             // depth groups per block (8 waves = 512 threads)
#define BINS_ (D_/GRP_)    // 12 bins per group
#define NCHUNK_ (HW_/PIX_) // 240

// Prep: mats (block 0) + transpose/fp16 of cur and look (interleaved [px][16ch]).
__global__ __launch_bounds__(256) void prep_kernel(
    const float* __restrict__ cur, const float* __restrict__ look,
    const float* __restrict__ poses, const float* __restrict__ Kmat,
    __half* __restrict__ curH, __half* __restrict__ lookH,
    float* __restrict__ mats)
{
  int tid = threadIdx.x;
  int bid = blockIdx.x;
  if (bid == 0 && tid < B_*F_) {
    int t = tid, b = t / F_;
    const float* T  = poses + t*16;
    const float* Kb = Kmat + b*16;
    float sum = 0.f;
    #pragma unroll
    for (int i = 0; i < 16; ++i) sum += T[i];
    #pragma unroll
    for (int i = 0; i < 3; ++i) {
      #pragma unroll
      for (int j = 0; j < 4; ++j) {
        float v = 0.f;
        #pragma unroll
        for (int k = 0; k < 4; ++k) v += Kb[i*4+k] * T[k*4+j];
        mats[t*16 + i*4 + j] = v;
      }
    }
    mats[t*16 + 12] = (sum != 0.f) ? 1.f : 0.f;
  }
  int px_l = tid & 127;
  int h    = tid >> 7;                 // 0 or 1 (channel half)
  int gp   = bid*128 + px_l;           // global pixel id over cur then look
  const float* src;
  __half* dst;
  int hw, c0 = h*8;
  if (gp < B_*HW_) {
    hw = gp % HW_;
    int s = gp / HW_;
    src = cur + (size_t)s*C_*HW_ + hw;
    dst = curH + (size_t)gp*C_ + c0;
  } else {
    int j = gp - B_*HW_;
    hw = j % HW_;
    int s = j / HW_;
    src = look + (size_t)s*C_*HW_ + hw;
    dst = lookH + (size_t)j*C_ + c0;
  }
  __half2 hh[4];
  #pragma unroll
  for (int j = 0; j < 4; ++j)
    hh[j] = __floats2half2_rn(src[(size_t)(c0+2*j)*HW_], src[(size_t)(c0+2*j+1)*HW_]);
  *reinterpret_cast<uint4*>(dst) = *reinterpret_cast<uint4*>(&hh[0]);
}

// Fused cost + finalize. Wave = 32 pixels x 2 lanes (lane = 2*px+h).
// Lane h: computes PROJECTION for frame h only (exact reference op order);
// pair exchanges {offset, 4 weights, ok} via shfl_xor(1). Each lane loads its
// 8 channels (16B, dense stride) for BOTH frames and interps both; full-frame
// sums completed via one shfl per frame. costsum order commutative ->
// bit-identical results on the h==0 writer lanes.
__global__ __launch_bounds__(512, 4) void fused_kernel(
    const __half* __restrict__ curH, const __half* __restrict__ lookH,
    const float* __restrict__ mats, const float* __restrict__ invK,
    const float* __restrict__ dbins,
    float* __restrict__ cost, float* __restrict__ missing)
{
  int tid  = threadIdx.x;
  int lane = tid & 63;
  int px_l = lane >> 1;               // 0..31
  int h    = lane & 1;                // channel half AND projection frame
  int grp  = tid >> 6;                // 0..7 (wave index)
  int bid  = blockIdx.x;
  int chunk = bid % NCHUNK_;
  int b = bid / NCHUNK_;
  int hw = chunk*PIX_ + px_l;
  int x = hw % W_, y = hw / W_;
  size_t obase = ((size_t)(b*D_ + grp*BINS_))*HW_ + hw;

  float res[BINS_];
  #pragma unroll
  for (int dd = 0; dd < BINS_; ++dd) res[dd] = 0.f;
  float lmax = 0.f;
  bool interior = (x >= 2 && x < W_-2 && y >= 2 && y < H_-2);  // pair-uniform
  if (interior) {
    const float* iK = invK + b*16;
    float xf = (float)x, yf = (float)y;
    float r0 = iK[0]*xf + iK[1]*yf + iK[2];
    float r1 = iK[4]*xf + iK[5]*yf + iK[6];
    float r2 = iK[8]*xf + iK[9]*yf + iK[10];
    // this half's 8 current-feature channels (dense 16B-stride wave load)
    __half2 cc2[4];
    *reinterpret_cast<uint4*>(&cc2[0]) =
        *reinterpret_cast<const uint4*>(curH + (size_t)(b*HW_ + hw)*C_ + h*8);
    // projection rows for MY frame only (lane h -> frame h)
    float Mv[13];
    {
      const float* Mt = mats + (b*F_+h)*16;
      #pragma unroll
      for (int i = 0; i < 13; ++i) Mv[i] = Mt[i];
    }
    const __half* fb_m = lookH + (size_t)((b*F_+h)*HW_)*C_     + h*8;  // my frame
    const __half* fb_o = lookH + (size_t)((b*F_+(1-h))*HW_)*C_ + h*8;  // other frame
    #pragma unroll
    for (int dd = 0; dd < BINS_; ++dd) {
      float dep = dbins[grp*BINS_ + dd];
      float p0 = dep*r0, p1 = dep*r1, p2 = dep*r2;
      // --- projection for my frame (reference op order) ---
      float camx = Mv[0]*p0 + Mv[1]*p1 + Mv[2] *p2 + Mv[3];
      float camy = Mv[4]*p0 + Mv[5]*p1 + Mv[6] *p2 + Mv[7];
      float camz = Mv[8]*p0 + Mv[9]*p1 + Mv[10]*p2 + Mv[11];
      float z  = camz + 1e-7f;
      float px = camx / z;
      float py = camy / z;
      bool okm = (Mv[12] != 0.f) && (px >= 2.f) && (px <= (float)(W_-2))
                                 && (py >= 2.f) && (py <= (float)(H_-2));
      float x0 = floorf(px), y0 = floorf(py);
      float fx = px - x0, fy = py - y0;
      fx = fminf(fmaxf(fx, 0.f), 1.f);
      fy = fminf(fmaxf(fy, 0.f), 1.f);
      int xi = min(max((int)x0, 0), W_-2);
      int yi = min(max((int)y0, 0), H_-2);
      int offm = (yi*W_ + xi)*C_;
      float w00m = (1.f-fx)*(1.f-fy), w10m = fx*(1.f-fy);
      float w01m = (1.f-fx)*fy,       w11m = fx*fy;
      // --- pair exchange: partner computed the OTHER frame ---
      int   offo = __shfl_xor(offm, 1, 64);
      float w00o = __shfl_xor(w00m, 1, 64);
      float w10o = __shfl_xor(w10m, 1, 64);
      float w01o = __shfl_xor(w01m, 1, 64);
      float w11o = __shfl_xor(w11m, 1, 64);
      int   oko_i = __shfl_xor((int)okm, 1, 64);
      // --- 8 tap loads (16B each, my channel half, both frames) ---
      uint4 t[8];
      {
        const __half* bm = fb_m + offm;
        const __half* bo = fb_o + offo;
        t[0] = *reinterpret_cast<const uint4*>(bm);
        t[1] = *reinterpret_cast<const uint4*>(bm + C_);
        t[2] = *reinterpret_cast<const uint4*>(bm + W_*C_);
        t[3] = *reinterpret_cast<const uint4*>(bm + W_*C_ + C_);
        t[4] = *reinterpret_cast<const uint4*>(bo);
        t[5] = *reinterpret_cast<const uint4*>(bo + C_);
        t[6] = *reinterpret_cast<const uint4*>(bo + W_*C_);
        t[7] = *reinterpret_cast<const uint4*>(bo + W_*C_ + C_);
      }
      // --- interpolation for both frames on my 8 channels ---
      float s_half_m, s_half_o;
      {
        __half2 w00h = __float2half2_rn(w00m);
        __half2 w10h = __float2half2_rn(w10m);
        __half2 w01h = __float2half2_rn(w01m);
        __half2 w11h = __float2half2_rn(w11m);
        const __half2* a00 = reinterpret_cast<const __half2*>(&t[0]);
        const __half2* a10 = reinterpret_cast<const __half2*>(&t[1]);
        const __half2* a01 = reinterpret_cast<const __half2*>(&t[2]);
        const __half2* a11 = reinterpret_cast<const __half2*>(&t[3]);
        __half2 acc0 = __float2half2_rn(0.f);
        __half2 acc1 = __float2half2_rn(0.f);
        #pragma unroll
        for (int i = 0; i < 4; ++i) {
          __half2 v = __hmul2(w00h, a00[i]);
          v = __hfma2(w10h, a10[i], v);
          v = __hfma2(w01h, a01[i], v);
          v = __hfma2(w11h, a11[i], v);
          __half2 dsub = __habs2(__hsub2(v, cc2[i]));
          if (i & 1) acc1 = __hadd2(acc1, dsub);
          else       acc0 = __hadd2(acc0, dsub);
        }
        float2 f0 = __half22float2(acc0);
        float2 f1 = __half22float2(acc1);
        s_half_m = (f0.x + f0.y) + (f1.x + f1.y);
      }
      {
        __half2 w00h = __float2half2_rn(w00o);
        __half2 w10h = __float2half2_rn(w10o);
        __half2 w01h = __float2half2_rn(w01o);
        __half2 w11h = __float2half2_rn(w11o);
        const __half2* a00 = reinterpret_cast<const __half2*>(&t[4]);
        const __half2* a10 = reinterpret_cast<const __half2*>(&t[5]);
        const __half2* a01 = reinterpret_cast<const __half2*>(&t[6]);
        const __half2* a11 = reinterpret_cast<const __half2*>(&t[7]);
        __half2 acc0 = __float2half2_rn(0.f);
        __half2 acc1 = __float2half2_rn(0.f);
        #pragma unroll
        for (int i = 0; i < 4; ++i) {
          __half2 v = __hmul2(w00h, a00[i]);
          v = __hfma2(w10h, a10[i], v);
          v = __hfma2(w01h, a01[i], v);
          v = __hfma2(w11h, a11[i], v);
          __half2 dsub = __habs2(__hsub2(v, cc2[i]));
          if (i & 1) acc1 = __hadd2(acc1, dsub);
          else       acc0 = __hadd2(acc0, dsub);
        }
        float2 f0 = __half22float2(acc0);
        float2 f1 = __half22float2(acc1);
        s_half_o = (f0.x + f0.y) + (f1.x + f1.y);
      }
      // full-frame sums: partner's "other" is my frame's missing half.
      float s_m = s_half_m + __shfl_xor(s_half_o, 1, 64);  // my frame, 16 ch
      float s_o = s_half_o + __shfl_xor(s_half_m, 1, 64);  // other frame, 16 ch
      float diffs_m = okm          ? s_m * (1.f/16.f) : 0.f;
      float diffs_o = (oko_i != 0) ? s_o * (1.f/16.f) : 0.f;
      float costsum = diffs_m + diffs_o;                   // commutative
      float cnt = ((diffs_m > 0.f) ? 1.f : 0.f) + ((diffs_o > 0.f) ? 1.f : 0.f);
      float r = costsum / (cnt + 1e-7f);
      res[dd] = r;
      lmax = fmaxf(lmax, r);
    }
  }

  // per-pixel max over the 8 depth-groups (h==0 lanes carry the result)
  __shared__ float lmaxs[GRP_][PIX_];
  if (h == 0) lmaxs[grp][px_l] = lmax;
  __syncthreads();
  float pmax = lmaxs[0][px_l];
  #pragma unroll
  for (int g = 1; g < GRP_; ++g) pmax = fmaxf(pmax, lmaxs[g][px_l]);

  // write cost (missing-filled) + missing from h==0 lanes (nt stores)
  if (h == 0) {
    #pragma unroll
    for (int dd = 0; dd < BINS_; ++dd) {
      size_t o = obase + (size_t)dd*HW_;
      float v = res[dd];
      float miss = (v == 0.f) ? 1.f : 0.f;
      __builtin_nontemporal_store(miss ? pmax : v, &cost[o]);
      __builtin_nontemporal_store(miss, &missing[o]);
    }
  }
}

extern "C" void kernel_launch(void* const* d_in, const int* in_sizes, int n_in,
                              void* d_out, int out_size, void* d_ws, size_t ws_size,
                              hipStream_t stream) {
  const float* cur   = (const float*)d_in[0];
  const float* look  = (const float*)d_in[1];
  const float* poses = (const float*)d_in[2];
  const float* Km    = (const float*)d_in[3];
  const float* invK  = (const float*)d_in[4];
  const float* dbins = (const float*)d_in[5];

  float* out_cost = (float*)d_out;
  float* out_miss = out_cost + (size_t)B_*D_*HW_;

  char*   ws    = (char*)d_ws;
  float*  mats  = (float*)ws;                                       // 128 floats
  __half* curH  = (__half*)(ws + 1024);                             // B*HW*C f16
  __half* lookH = (__half*)(ws + 1024 + (size_t)B_*HW_*C_*2);       // B*F*HW*C f16

  prep_kernel<<<(B_*HW_ + B_*F_*HW_)/128, 256, 0, stream>>>(
      cur, look, poses, Km, curH, lookH, mats);
  fused_kernel<<<B_*NCHUNK_, 512, 0, stream>>>(
      curH, lookH, mats, invK, dbins, out_cost, out_miss);
}

// Round 17
// 40.659 us; speedup vs baseline: 1.4187x; 1.2918x over previous
//
#include <hip/hip_runtime.h>
#include <hip/hip_fp16.h>

#define B_ 4
#define F_ 2
#define C_ 16
#define H_ 48
#define W_ 160
#define D_ 96
#define HW_ (H_*W_)
#define PIX_ 64            // pixels per block (one wave = 64 px at one depth-group)
#define GRP_ 8             // depth groups per block (PIX_*GRP_ = 512 threads)
#define BINS_ (D_/GRP_)    // 12 bins per group
#define NCHUNK_ (HW_/PIX_) // 120

// Prep: mats (block 0) + transpose/fp16 of cur and look.
// 2 threads per pixel (8 channels each) -> 720 blocks for TLP.
__global__ __launch_bounds__(256) void prep_kernel(
    const float* __restrict__ cur, const float* __restrict__ look,
    const float* __restrict__ poses, const float* __restrict__ Kmat,
    __half* __restrict__ curH, __half* __restrict__ lookH,
    float* __restrict__ mats)
{
  int tid = threadIdx.x;
  int bid = blockIdx.x;
  if (bid == 0 && tid < B_*F_) {
    int t = tid, b = t / F_;
    const float* T  = poses + t*16;
    const float* Kb = Kmat + b*16;
    float sum = 0.f;
    #pragma unroll
    for (int i = 0; i < 16; ++i) sum += T[i];
    #pragma unroll
    for (int i = 0; i < 3; ++i) {
      #pragma unroll
      for (int j = 0; j < 4; ++j) {
        float v = 0.f;
        #pragma unroll
        for (int k = 0; k < 4; ++k) v += Kb[i*4+k] * T[k*4+j];
        mats[t*16 + i*4 + j] = v;
      }
    }
    mats[t*16 + 12] = (sum != 0.f) ? 1.f : 0.f;
  }
  int px_l = tid & 127;
  int h    = tid >> 7;                 // 0 or 1 (channel half)
  int gp   = bid*128 + px_l;           // global pixel id over cur then look
  const float* src;
  __half* dst;
  int hw, c0 = h*8;
  if (gp < B_*HW_) {
    hw = gp % HW_;
    int s = gp / HW_;
    src = cur + (size_t)s*C_*HW_ + hw;
    dst = curH + (size_t)gp*C_ + c0;
  } else {
    int j = gp - B_*HW_;
    hw = j % HW_;
    int s = j / HW_;
    src = look + (size_t)s*C_*HW_ + hw;
    dst = lookH + (size_t)j*C_ + c0;
  }
  __half2 hh[4];
  #pragma unroll
  for (int j = 0; j < 4; ++j)
    hh[j] = __floats2half2_rn(src[(size_t)(c0+2*j)*HW_], src[(size_t)(c0+2*j+1)*HW_]);
  *reinterpret_cast<uint4*>(dst) = *reinterpret_cast<uint4*>(&hh[0]);
}

// Fused cost + finalize. Block = 64 pixels x 8 depth-groups (12 bins each).
// Each WAVE = 64 consecutive pixels at one depth-group. Unconditional batched
// tap loads (rounds 6-8 lesson: no loop-carried conditional state).
// Output stores are nontemporal (no reuse; keep L2 for the gather streams).
__global__ __launch_bounds__(512, 4) void fused_kernel(
    const __half* __restrict__ curH, const __half* __restrict__ lookH,
    const float* __restrict__ mats, const float* __restrict__ invK,
    const float* __restrict__ dbins,
    float* __restrict__ cost, float* __restrict__ missing)
{
  int tid = threadIdx.x;
  int pix = tid & (PIX_-1);
  int grp = tid >> 6;                 // 0..7 (wave index)
  int bid = blockIdx.x;
  int chunk = bid % NCHUNK_;
  int b = bid / NCHUNK_;
  int hw = chunk*PIX_ + pix;
  int x = hw % W_, y = hw / W_;
  size_t obase = ((size_t)(b*D_ + grp*BINS_))*HW_ + hw;

  float res[BINS_];
  #pragma unroll
  for (int dd = 0; dd < BINS_; ++dd) res[dd] = 0.f;
  float lmax = 0.f;
  bool interior = (x >= 2 && x < W_-2 && y >= 2 && y < H_-2);
  if (interior) {
    const float* iK = invK + b*16;
    float xf = (float)x, yf = (float)y;
    float r0 = iK[0]*xf + iK[1]*yf + iK[2];
    float r1 = iK[4]*xf + iK[5]*yf + iK[6];
    float r2 = iK[8]*xf + iK[9]*yf + iK[10];
    __half2 cc2[8];
    {
      const uint4* cur4 = reinterpret_cast<const uint4*>(curH + (size_t)(b*HW_ + hw)*C_);
      *reinterpret_cast<uint4*>(&cc2[0]) = cur4[0];
      *reinterpret_cast<uint4*>(&cc2[4]) = cur4[1];
    }
    // wave-uniform projection rows (b uniform per block, f static)
    float Mv[2][13];
    #pragma unroll
    for (int f = 0; f < F_; ++f) {
      const float* Mt = mats + (b*F_+f)*16;
      #pragma unroll
      for (int i = 0; i < 13; ++i) Mv[f][i] = Mt[i];
    }
    #pragma unroll
    for (int dd = 0; dd < BINS_; ++dd) {
      float dep = dbins[grp*BINS_ + dd];
      float p0 = dep*r0, p1 = dep*r1, p2 = dep*r2;
      // --- phase 1: addresses + weights for both frames ---
      const __half* bases[F_];
      float w00f[F_], w10f[F_], w01f[F_], w11f[F_];
      bool okf[F_];
      #pragma unroll
      for (int f = 0; f < F_; ++f) {
        float camx = Mv[f][0]*p0 + Mv[f][1]*p1 + Mv[f][2] *p2 + Mv[f][3];
        float camy = Mv[f][4]*p0 + Mv[f][5]*p1 + Mv[f][6] *p2 + Mv[f][7];
        float camz = Mv[f][8]*p0 + Mv[f][9]*p1 + Mv[f][10]*p2 + Mv[f][11];
        float z  = camz + 1e-7f;
        float px = camx / z;
        float py = camy / z;
        okf[f] = (Mv[f][12] != 0.f) && (px >= 2.f) && (px <= (float)(W_-2))
                                    && (py >= 2.f) && (py <= (float)(H_-2));
        float x0 = floorf(px), y0 = floorf(py);
        float fx = px - x0, fy = py - y0;
        fx = fminf(fmaxf(fx, 0.f), 1.f);
        fy = fminf(fmaxf(fy, 0.f), 1.f);
        int xi = min(max((int)x0, 0), W_-2);
        int yi = min(max((int)y0, 0), H_-2);
        bases[f] = lookH + ((size_t)((b*F_+f)*HW_) + yi*W_ + xi)*C_;
        w00f[f] = (1.f-fx)*(1.f-fy); w10f[f] = fx*(1.f-fy);
        w01f[f] = (1.f-fx)*fy;       w11f[f] = fx*fy;
      }
      // --- phase 2: issue all 16 tap loads ---
      uint4 t[16];
      #pragma unroll
      for (int f = 0; f < F_; ++f) {
        const uint4* rr0 = reinterpret_cast<const uint4*>(bases[f]);
        const uint4* rr1 = reinterpret_cast<const uint4*>(bases[f] + W_*C_);
        #pragma unroll
        for (int i = 0; i < 4; ++i) t[f*8+i]   = rr0[i];
        #pragma unroll
        for (int i = 0; i < 4; ++i) t[f*8+4+i] = rr1[i];
      }
      // --- phase 3: fp16 interpolation + L1 diff ---
      float costsum = 0.f, cnt = 0.f;
      #pragma unroll
      for (int f = 0; f < F_; ++f) {
        __half2 w00h = __float2half2_rn(w00f[f]);
        __half2 w10h = __float2half2_rn(w10f[f]);
        __half2 w01h = __float2half2_rn(w01f[f]);
        __half2 w11h = __float2half2_rn(w11f[f]);
        const __half2* a00 = reinterpret_cast<const __half2*>(&t[f*8+0]);
        const __half2* a10 = reinterpret_cast<const __half2*>(&t[f*8+2]);
        const __half2* a01 = reinterpret_cast<const __half2*>(&t[f*8+4]);
        const __half2* a11 = reinterpret_cast<const __half2*>(&t[f*8+6]);
        __half2 acc0 = __float2half2_rn(0.f);
        __half2 acc1 = __float2half2_rn(0.f);
        #pragma unroll
        for (int i = 0; i < 8; ++i) {
          __half2 v = __hmul2(w00h, a00[i]);
          v = __hfma2(w10h, a10[i], v);
          v = __hfma2(w01h, a01[i], v);
          v = __hfma2(w11h, a11[i], v);
          __half2 dsub = __habs2(__hsub2(v, cc2[i]));
          if (i & 1) acc1 = __hadd2(acc1, dsub);
          else       acc0 = __hadd2(acc0, dsub);
        }
        float2 f0 = __half22float2(acc0);
        float2 f1 = __half22float2(acc1);
        float s = (f0.x + f0.y) + (f1.x + f1.y);
        float diffs = s * (1.f/16.f);
        diffs = okf[f] ? diffs : 0.f;
        costsum += diffs;
        cnt     += (diffs > 0.f) ? 1.f : 0.f;
      }
      float r = costsum / (cnt + 1e-7f);
      res[dd] = r;
      lmax = fmaxf(lmax, r);
    }
  }

  // per-pixel max over the 8 depth-groups
  __shared__ float lmaxs[GRP_][PIX_];
  lmaxs[grp][pix] = lmax;
  __syncthreads();
  float pmax = lmaxs[0][pix];
  #pragma unroll
  for (int g = 1; g < GRP_; ++g) pmax = fmaxf(pmax, lmaxs[g][pix]);

  // write cost (missing-filled) + missing, straight from registers (nt stores)
  #pragma unroll
  for (int dd = 0; dd < BINS_; ++dd) {
    size_t o = obase + (size_t)dd*HW_;
    float v = res[dd];
    float miss = (v == 0.f) ? 1.f : 0.f;
    __builtin_nontemporal_store(miss ? pmax : v, &cost[o]);
    __builtin_nontemporal_store(miss, &missing[o]);
  }
}

extern "C" void kernel_launch(void* const* d_in, const int* in_sizes, int n_in,
                              void* d_out, int out_size, void* d_ws, size_t ws_size,
                              hipStream_t stream) {
  const float* cur   = (const float*)d_in[0];
  const float* look  = (const float*)d_in[1];
  const float* poses = (const float*)d_in[2];
  const float* Km    = (const float*)d_in[3];
  const float* invK  = (const float*)d_in[4];
  const float* dbins = (const float*)d_in[5];

  float* out_cost = (float*)d_out;
  float* out_miss = out_cost + (size_t)B_*D_*HW_;

  char*   ws    = (char*)d_ws;
  float*  mats  = (float*)ws;                                       // 128 floats
  __half* curH  = (__half*)(ws + 1024);                             // B*HW*C f16
  __half* lookH = (__half*)(ws + 1024 + (size_t)B_*HW_*C_*2);       // B*F*HW*C f16

  prep_kernel<<<(B_*HW_ + B_*F_*HW_)/128, 256, 0, stream>>>(
      cur, look, poses, Km, curH, lookH, mats);
  fused_kernel<<<B_*NCHUNK_, 512, 0, stream>>>(
      curH, lookH, mats, invK, dbins, out_cost, out_miss);
}